// Round 5
// baseline (1453.621 us; speedup 1.0000x reference)
//
#include <hip/hip_runtime.h>

// ---------------------------------------------------------------------------
// GIN 3-layer: h_{l+1} = act((h + agg(h)) @ W + b)
// Restructured: z = act(h) @ W ; a = b + z + agg(z)   (agg commutes with W)
// Round 5: EDGE-PARALLEL aggregation, take 2.
//   - block owns 64 dst rows; CSR edge range is contiguous (dst-sorted)
//   - 16-lane groups take one edge each: a wave reads 4 FULL 256B z-rows per
//     load instruction (coalesced); 64 edges/block-iter, 4 slots in flight
//   - accumulate with ds_add_f32 via __hip_atomic_fetch_add(WORKGROUP scope)
//     (round-1 used atomicAdd(generic float*) -> CAS loop -> 100x slowdown;
//     that poisoned the whole design, not the LDS-atomic idea itself)
//   - trash row 64 absorbs clamped tail edges -> zero divergence
//   - MFMA phase reads A-fragments from the LDS fp32 tile (validated in r1)
// ---------------------------------------------------------------------------

typedef __attribute__((ext_vector_type(8))) short short8;
typedef __attribute__((ext_vector_type(4))) float f32x4;
typedef unsigned short ushort_t;
typedef unsigned int uint_t;

__device__ inline ushort_t bf16_rne(float f) {
  uint_t u = __float_as_uint(f);
  uint_t r = (u + 0x7FFFu + ((u >> 16) & 1u)) >> 16;
  return (ushort_t)r;
}
__device__ inline float bf16_to_f32(ushort_t h) {
  return __uint_as_float(((uint_t)h) << 16);
}
__device__ __forceinline__ void lds_add(float* p, float v) {
  // __shared__-derived pointer + workgroup scope -> ds_add_f32 (no CAS loop)
  __hip_atomic_fetch_add(p, v, __ATOMIC_RELAXED, __HIP_MEMORY_SCOPE_WORKGROUP);
}

// ---- edge dtype detection: int64 (reference decl) vs int32 (JAX x64-off) ----
__global__ __launch_bounds__(256) void k_detect(const int* __restrict__ ew,
                                                int* __restrict__ flag, int E) {
  int i = blockIdx.x * 256 + threadIdx.x;
  int idx = 2 * i + 1;
  if (idx < 2 * E) {
    if (ew[idx] != 0) atomicOr(flag, 1);    // nonzero odd word => int32 layout
  }
}

// ---- CSR build -------------------------------------------------------------
__global__ __launch_bounds__(256) void k_hist(const void* __restrict__ edges,
                                              const int* __restrict__ flag,
                                              int* __restrict__ counts, int E) {
  int e = blockIdx.x * 256 + threadIdx.x;
  if (e >= E) return;
  int d;
  if (*flag) d = ((const int*)edges)[E + e];
  else       d = (int)((const long long*)edges)[E + e];
  atomicAdd(&counts[d], 1);
}

__global__ __launch_bounds__(256) void k_scan1(const int* __restrict__ counts,
                                               int* __restrict__ offs,
                                               int* __restrict__ bsum, int N) {
  __shared__ int s[256];
  int t = threadIdx.x;
  int base = blockIdx.x * 1024 + t * 4;
  int c0 = 0, c1 = 0, c2 = 0, c3 = 0;
  if (base + 0 < N) c0 = counts[base + 0];
  if (base + 1 < N) c1 = counts[base + 1];
  if (base + 2 < N) c2 = counts[base + 2];
  if (base + 3 < N) c3 = counts[base + 3];
  int mySum = c0 + c1 + c2 + c3;
  s[t] = mySum;
  __syncthreads();
  for (int d = 1; d < 256; d <<= 1) {
    int v = (t >= d) ? s[t - d] : 0;
    __syncthreads();
    s[t] += v;
    __syncthreads();
  }
  int excl = s[t] - mySum;
  if (base + 0 < N) offs[base + 0] = excl;
  if (base + 1 < N) offs[base + 1] = excl + c0;
  if (base + 2 < N) offs[base + 2] = excl + c0 + c1;
  if (base + 3 < N) offs[base + 3] = excl + c0 + c1 + c2;
  if (t == 255) bsum[blockIdx.x] = s[255];
}

__global__ __launch_bounds__(128) void k_scan2(int* __restrict__ bsum, int nb) {
  __shared__ int s[128];
  int t = threadIdx.x;
  int v = (t < nb) ? bsum[t] : 0;
  s[t] = v;
  __syncthreads();
  for (int d = 1; d < 128; d <<= 1) {
    int u = (t >= d) ? s[t - d] : 0;
    __syncthreads();
    s[t] += u;
    __syncthreads();
  }
  if (t < nb) bsum[t] = s[t] - v;
}

__global__ __launch_bounds__(256) void k_scan3(int* __restrict__ offs,
                                               const int* __restrict__ bsum,
                                               int* __restrict__ cursor,
                                               int N, int E) {
  int t = threadIdx.x;
  int add = bsum[blockIdx.x];
  int base = blockIdx.x * 1024 + t * 4;
#pragma unroll
  for (int j = 0; j < 4; j++) {
    int i = base + j;
    if (i < N) { int v = offs[i] + add; offs[i] = v; cursor[i] = v; }
  }
  if (blockIdx.x == 0 && t == 0) offs[N] = E;
}

__global__ __launch_bounds__(256) void k_fill(const void* __restrict__ edges,
                                              const int* __restrict__ flag,
                                              int* __restrict__ cursor,
                                              int2* __restrict__ epair, int E) {
  int e = blockIdx.x * 256 + threadIdx.x;
  if (e >= E) return;
  int s, d;
  if (*flag) {
    const int* p = (const int*)edges;
    s = p[e]; d = p[E + e];
  } else {
    const long long* p = (const long long*)edges;
    s = (int)p[e]; d = (int)p[E + e];
  }
  int pos = atomicAdd(&cursor[d], 1);
  epair[pos] = make_int2(s, d);
}

// ---- W repack into MFMA B-fragment order (hi/lo split bf16) -----------------
__global__ __launch_bounds__(256) void k_repack(
    const float* __restrict__ W1, const float* __restrict__ W2,
    const float* __restrict__ W3,
    ushort_t* __restrict__ h1, ushort_t* __restrict__ l1,
    ushort_t* __restrict__ h2, ushort_t* __restrict__ l2,
    ushort_t* __restrict__ h3, ushort_t* __restrict__ l3) {
  int idx = blockIdx.x * 256 + threadIdx.x;
  const float* W; ushort_t* H; ushort_t* L; int NC; int i;
  if (idx < 16384)      { W = W1; H = h1; L = l1; NC = 128; i = idx; }
  else if (idx < 32768) { W = W2; H = h2; L = l2; NC = 128; i = idx - 16384; }
  else if (idx < 40960) { W = W3; H = h3; L = l3; NC = 64;  i = idx - 32768; }
  else return;
  int j = i & 7;
  int lane = (i >> 3) & 63;
  int NT = NC >> 4;
  int tile = (i >> 9) & (NT - 1);
  int ks = i >> (9 + (NC == 128 ? 3 : 2));
  int k = ks * 32 + (lane >> 4) * 8 + j;
  int n = tile * 16 + (lane & 15);
  float v = W[(size_t)k * NC + n];
  ushort_t hi = bf16_rne(v);
  ushort_t lo = bf16_rne(v - bf16_to_f32(hi));
  H[i] = hi; L[i] = lo;
}

// ---- layer 1 GEMM: Z(bf16)[M x NC] = A(fp32)[M x 128] @ W -------------------
template <int NC>
__global__ __launch_bounds__(256) void k_gemm_mfma(
    const float* __restrict__ A, const ushort_t* __restrict__ Bhi,
    const ushort_t* __restrict__ Blo, ushort_t* __restrict__ Z, int M) {
  constexpr int NT = NC / 16;
  int lane = threadIdx.x & 63;
  int wave = threadIdx.x >> 6;
  int row0 = blockIdx.x * 64 + wave * 16;
  int m = lane & 15;
  int q = lane >> 4;
  int grow = row0 + m;
  bool rowok = (grow < M);

  f32x4 acc[NT];
#pragma unroll
  for (int t = 0; t < NT; t++) { acc[t][0] = 0.f; acc[t][1] = 0.f; acc[t][2] = 0.f; acc[t][3] = 0.f; }

  const float* arow = A + (size_t)(rowok ? grow : 0) * 128 + q * 8;

#pragma unroll
  for (int ks = 0; ks < 4; ks++) {
    float av[8];
    *(float4*)(av)     = *(const float4*)(arow + ks * 32);
    *(float4*)(av + 4) = *(const float4*)(arow + ks * 32 + 4);
    short8 ahi, alo;
#pragma unroll
    for (int j = 0; j < 8; j++) {
      float v = av[j];
      ushort_t hi = bf16_rne(v);
      ahi[j] = (short)hi;
      alo[j] = (short)bf16_rne(v - bf16_to_f32(hi));
    }
#pragma unroll
    for (int t = 0; t < NT; t++) {
      const short8 bh = *(const short8*)(Bhi + (((size_t)ks * NT + t) * 64 + lane) * 8);
      const short8 bl = *(const short8*)(Blo + (((size_t)ks * NT + t) * 64 + lane) * 8);
      acc[t] = __builtin_amdgcn_mfma_f32_16x16x32_bf16(ahi, bh, acc[t], 0, 0, 0);
      acc[t] = __builtin_amdgcn_mfma_f32_16x16x32_bf16(ahi, bl, acc[t], 0, 0, 0);
      acc[t] = __builtin_amdgcn_mfma_f32_16x16x32_bf16(alo, bh, acc[t], 0, 0, 0);
    }
  }

  int zrow = row0 + q * 4;
#pragma unroll
  for (int r = 0; r < 4; r++) {
    if (zrow + r < M) {
#pragma unroll
      for (int t = 0; t < NT; t++)
        Z[(size_t)(zrow + r) * NC + t * 16 + m] = bf16_rne(acc[t][r]);
    }
  }
}

// ---- fused agg + GEMM (layers 2,3): edge-parallel + ds_add_f32 --------------
// LDS tile sacc[65][132] fp32 (row 64 = trash). Init = bias + Zin[own].
// Edge phase: group g = t>>4 (16 groups), lane16 = t&15; per block-iter the
// block covers 64 contiguous edges (4 slots x 16 groups); each group reads a
// full 256B z-row (16 lanes x 16B, coalesced) and ds_add's 8 cols per lane.
template <int NC>
__global__ __launch_bounds__(256) void k_fused(
    const ushort_t* __restrict__ Zin, const int2* __restrict__ ep,
    const int* __restrict__ offs, const float* __restrict__ bias,
    const ushort_t* __restrict__ Bhi, const ushort_t* __restrict__ Blo,
    ushort_t* __restrict__ Zout, int M) {
  constexpr int NT = NC / 16;
  constexpr int S = 132;
  __shared__ float sacc[65 * S];

  int t = threadIdx.x;
  int row0 = blockIdx.x * 64;
  int rows = min(64, M - row0);

  // ---- init: sacc[r][c] = bias[c] + Zin[row0+r][c], r=t>>2, cols (t&3)*32.. ----
  {
    int r = t >> 2, sub = t & 3;
    int grow = row0 + r;
    const ushort_t* zr = Zin + (size_t)(grow < M ? grow : 0) * 128 + sub * 32;
    const float* bq = bias + sub * 32;
    float* dst = sacc + r * S + sub * 32;
#pragma unroll
    for (int kk = 0; kk < 4; kk++) {
      short8 u = *(const short8*)(zr + kk * 8);
      float4 b0 = *(const float4*)(bq + kk * 8);
      float4 b1 = *(const float4*)(bq + kk * 8 + 4);
      float v0 = b0.x + bf16_to_f32((ushort_t)u[0]);
      float v1 = b0.y + bf16_to_f32((ushort_t)u[1]);
      float v2 = b0.z + bf16_to_f32((ushort_t)u[2]);
      float v3 = b0.w + bf16_to_f32((ushort_t)u[3]);
      float v4 = b1.x + bf16_to_f32((ushort_t)u[4]);
      float v5 = b1.y + bf16_to_f32((ushort_t)u[5]);
      float v6 = b1.z + bf16_to_f32((ushort_t)u[6]);
      float v7 = b1.w + bf16_to_f32((ushort_t)u[7]);
      *(float2*)(dst + kk * 8 + 0) = make_float2(v0, v1);
      *(float2*)(dst + kk * 8 + 2) = make_float2(v2, v3);
      *(float2*)(dst + kk * 8 + 4) = make_float2(v4, v5);
      *(float2*)(dst + kk * 8 + 6) = make_float2(v6, v7);
    }
  }
  __syncthreads();

  // ---- edge-parallel aggregation ----
  {
    int eb = offs[row0];
    int ee = offs[row0 + rows];
    int ne = ee - eb;
    int g = t >> 4;
    int lane16 = t & 15;
    int nb = (ne + 63) >> 6;
    const ushort_t* Zl = Zin + lane16 * 8;
    for (int it = 0; it < nb; ++it) {
      int e0 = eb + it * 64 + g;
      int e1 = e0 + 16, e2 = e0 + 32, e3 = e0 + 48;
      int em1 = ee - 1;
      int2 p0 = ep[min(e0, em1)];
      int2 p1 = ep[min(e1, em1)];
      int2 p2 = ep[min(e2, em1)];
      int2 p3 = ep[min(e3, em1)];
      short8 v0 = *(const short8*)(Zl + (size_t)p0.x * 128);
      short8 v1 = *(const short8*)(Zl + (size_t)p1.x * 128);
      short8 v2 = *(const short8*)(Zl + (size_t)p2.x * 128);
      short8 v3 = *(const short8*)(Zl + (size_t)p3.x * 128);
      int d0 = (e0 < ee) ? (p0.y - row0) : 64;
      int d1 = (e1 < ee) ? (p1.y - row0) : 64;
      int d2 = (e2 < ee) ? (p2.y - row0) : 64;
      int d3 = (e3 < ee) ? (p3.y - row0) : 64;
      float* a0 = sacc + d0 * S + lane16 * 8;
      float* a1 = sacc + d1 * S + lane16 * 8;
      float* a2 = sacc + d2 * S + lane16 * 8;
      float* a3 = sacc + d3 * S + lane16 * 8;
#pragma unroll
      for (int jj = 0; jj < 8; jj++) lds_add(a0 + jj, bf16_to_f32((ushort_t)v0[jj]));
#pragma unroll
      for (int jj = 0; jj < 8; jj++) lds_add(a1 + jj, bf16_to_f32((ushort_t)v1[jj]));
#pragma unroll
      for (int jj = 0; jj < 8; jj++) lds_add(a2 + jj, bf16_to_f32((ushort_t)v2[jj]));
#pragma unroll
      for (int jj = 0; jj < 8; jj++) lds_add(a3 + jj, bf16_to_f32((ushort_t)v3[jj]));
    }
  }
  __syncthreads();

  // ---- relu + split-bf16 + MFMA, A from LDS ----
  int lane = t & 63;
  int wave = t >> 6;
  int m = lane & 15;
  int q = lane >> 4;
  const float* ar = sacc + (wave * 16 + m) * S + q * 8;

  f32x4 acc[NT];
#pragma unroll
  for (int tt = 0; tt < NT; tt++) { acc[tt][0] = 0.f; acc[tt][1] = 0.f; acc[tt][2] = 0.f; acc[tt][3] = 0.f; }

#pragma unroll
  for (int ks = 0; ks < 4; ks++) {
    short8 ahi, alo;
#pragma unroll
    for (int jj = 0; jj < 8; jj += 2) {
      float2 vv = *(const float2*)(ar + ks * 32 + jj);
      float v0 = fmaxf(vv.x, 0.f);
      float v1 = fmaxf(vv.y, 0.f);
      ushort_t h0 = bf16_rne(v0);
      ahi[jj] = (short)h0;
      alo[jj] = (short)bf16_rne(v0 - bf16_to_f32(h0));
      ushort_t h1 = bf16_rne(v1);
      ahi[jj + 1] = (short)h1;
      alo[jj + 1] = (short)bf16_rne(v1 - bf16_to_f32(h1));
    }
#pragma unroll
    for (int tt = 0; tt < NT; tt++) {
      const short8 bh = *(const short8*)(Bhi + (((size_t)ks * NT + tt) * 64 + lane) * 8);
      const short8 bl = *(const short8*)(Blo + (((size_t)ks * NT + tt) * 64 + lane) * 8);
      acc[tt] = __builtin_amdgcn_mfma_f32_16x16x32_bf16(ahi, bh, acc[tt], 0, 0, 0);
      acc[tt] = __builtin_amdgcn_mfma_f32_16x16x32_bf16(ahi, bl, acc[tt], 0, 0, 0);
      acc[tt] = __builtin_amdgcn_mfma_f32_16x16x32_bf16(alo, bh, acc[tt], 0, 0, 0);
    }
  }

  int zrow = row0 + wave * 16 + q * 4;
#pragma unroll
  for (int rr = 0; rr < 4; rr++) {
    if (zrow + rr < M) {
#pragma unroll
      for (int tt = 0; tt < NT; tt++)
        Zout[(size_t)(zrow + rr) * NC + tt * 16 + m] = bf16_rne(acc[tt][rr]);
    }
  }
}

// ---- final agg (64 cols): edge-parallel + ds_add_f32 ------------------------
// 8-lane groups read full 128B z3-rows; 128 edges per block-iter.
__global__ __launch_bounds__(256) void k_agg64(const ushort_t* __restrict__ z,
                                               const int2* __restrict__ ep,
                                               const int* __restrict__ offs,
                                               const float* __restrict__ bias,
                                               float* __restrict__ out, int N) {
  constexpr int S = 68;
  __shared__ float sacc[65 * S];
  int t = threadIdx.x;
  int row0 = blockIdx.x * 64;
  int rows = min(64, N - row0);

  {
    int r = t >> 2, sub = t & 3;
    int grow = row0 + r;
    const ushort_t* zr = z + (size_t)(grow < N ? grow : 0) * 64 + sub * 16;
    const float* bq = bias + sub * 16;
    float* dst = sacc + r * S + sub * 16;
#pragma unroll
    for (int kk = 0; kk < 2; kk++) {
      short8 u = *(const short8*)(zr + kk * 8);
      float4 b0 = *(const float4*)(bq + kk * 8);
      float4 b1 = *(const float4*)(bq + kk * 8 + 4);
      float v0 = b0.x + bf16_to_f32((ushort_t)u[0]);
      float v1 = b0.y + bf16_to_f32((ushort_t)u[1]);
      float v2 = b0.z + bf16_to_f32((ushort_t)u[2]);
      float v3 = b0.w + bf16_to_f32((ushort_t)u[3]);
      float v4 = b1.x + bf16_to_f32((ushort_t)u[4]);
      float v5 = b1.y + bf16_to_f32((ushort_t)u[5]);
      float v6 = b1.z + bf16_to_f32((ushort_t)u[6]);
      float v7 = b1.w + bf16_to_f32((ushort_t)u[7]);
      *(float2*)(dst + kk * 8 + 0) = make_float2(v0, v1);
      *(float2*)(dst + kk * 8 + 2) = make_float2(v2, v3);
      *(float2*)(dst + kk * 8 + 4) = make_float2(v4, v5);
      *(float2*)(dst + kk * 8 + 6) = make_float2(v6, v7);
    }
  }
  __syncthreads();

  {
    int eb = offs[row0];
    int ee = offs[row0 + rows];
    int ne = ee - eb;
    int g = t >> 3;
    int lane8 = t & 7;
    int nb = (ne + 127) >> 7;
    const ushort_t* Zl = z + lane8 * 8;
    for (int it = 0; it < nb; ++it) {
      int e0 = eb + it * 128 + g;
      int e1 = e0 + 32, e2 = e0 + 64, e3 = e0 + 96;
      int em1 = ee - 1;
      int2 p0 = ep[min(e0, em1)];
      int2 p1 = ep[min(e1, em1)];
      int2 p2 = ep[min(e2, em1)];
      int2 p3 = ep[min(e3, em1)];
      short8 v0 = *(const short8*)(Zl + (size_t)p0.x * 64);
      short8 v1 = *(const short8*)(Zl + (size_t)p1.x * 64);
      short8 v2 = *(const short8*)(Zl + (size_t)p2.x * 64);
      short8 v3 = *(const short8*)(Zl + (size_t)p3.x * 64);
      int d0 = (e0 < ee) ? (p0.y - row0) : 64;
      int d1 = (e1 < ee) ? (p1.y - row0) : 64;
      int d2 = (e2 < ee) ? (p2.y - row0) : 64;
      int d3 = (e3 < ee) ? (p3.y - row0) : 64;
      float* a0 = sacc + d0 * S + lane8 * 8;
      float* a1 = sacc + d1 * S + lane8 * 8;
      float* a2 = sacc + d2 * S + lane8 * 8;
      float* a3 = sacc + d3 * S + lane8 * 8;
#pragma unroll
      for (int jj = 0; jj < 8; jj++) lds_add(a0 + jj, bf16_to_f32((ushort_t)v0[jj]));
#pragma unroll
      for (int jj = 0; jj < 8; jj++) lds_add(a1 + jj, bf16_to_f32((ushort_t)v1[jj]));
#pragma unroll
      for (int jj = 0; jj < 8; jj++) lds_add(a2 + jj, bf16_to_f32((ushort_t)v2[jj]));
#pragma unroll
      for (int jj = 0; jj < 8; jj++) lds_add(a3 + jj, bf16_to_f32((ushort_t)v3[jj]));
    }
  }
  __syncthreads();

  {
    int r = t >> 2, sub = t & 3;
    if (row0 + r < N) {
      float* op = out + (size_t)(row0 + r) * 64 + sub * 16;
      const float* sp = sacc + r * S + sub * 16;
#pragma unroll
      for (int kk = 0; kk < 4; kk++) {
        float4 o = make_float4(sp[kk * 4 + 0], sp[kk * 4 + 1],
                               sp[kk * 4 + 2], sp[kk * 4 + 3]);
        *(float4*)(op + kk * 4) = o;
      }
    }
  }
}

// ---------------------------------------------------------------------------
extern "C" void kernel_launch(void* const* d_in, const int* in_sizes, int n_in,
                              void* d_out, int out_size, void* d_ws, size_t ws_size,
                              hipStream_t stream) {
  const float* x  = (const float*)d_in[0];
  const void* edges = d_in[1];
  const float* W1 = (const float*)d_in[2];
  const float* b1 = (const float*)d_in[3];
  const float* W2 = (const float*)d_in[4];
  const float* b2 = (const float*)d_in[5];
  const float* W3 = (const float*)d_in[6];
  const float* b3 = (const float*)d_in[7];
  float* out = (float*)d_out;

  int N = in_sizes[0] / 128;   // 100000
  int E = in_sizes[1] / 2;     // 600000

  char* w = (char*)d_ws;
  size_t off = 0;
  auto alloc = [&](size_t bytes) -> void* {
    void* p = w + off;
    off = (off + bytes + 255) & ~(size_t)255;
    return p;
  };
  size_t curBytes = ((size_t)N * 4 + 255) & ~(size_t)255;
  int*   cursor = (int*)alloc(curBytes);     // degree counts, then fill cursor
  int*   flag   = (int*)alloc(4);            // adjacent: one memset covers both
  int2*  epair  = (int2*)alloc((size_t)E * 8);
  int*   offs   = (int*)alloc((size_t)(N + 1) * 4);
  int*   bsum   = (int*)alloc(4096);
  ushort_t* h1  = (ushort_t*)alloc(16384 * 2);
  ushort_t* l1  = (ushort_t*)alloc(16384 * 2);
  ushort_t* h2  = (ushort_t*)alloc(16384 * 2);
  ushort_t* l2  = (ushort_t*)alloc(16384 * 2);
  ushort_t* h3  = (ushort_t*)alloc(8192 * 2);
  ushort_t* l3  = (ushort_t*)alloc(8192 * 2);
  ushort_t* z1  = (ushort_t*)alloc((size_t)N * 128 * 2);  // bf16
  ushort_t* z2  = (ushort_t*)alloc((size_t)N * 128 * 2);  // bf16
  ushort_t* z3  = z1;                                     // reuse (N x 64 fits)

  int ge = (E + 255) / 256;
  int nb = (N + 1023) / 1024;

  hipMemsetAsync(cursor, 0, curBytes + 4, stream);
  k_detect<<<4, 256, 0, stream>>>((const int*)edges, flag, E);
  k_hist<<<ge, 256, 0, stream>>>(edges, flag, cursor, E);
  k_scan1<<<nb, 256, 0, stream>>>(cursor, offs, bsum, N);
  k_scan2<<<1, 128, 0, stream>>>(bsum, nb);
  k_scan3<<<nb, 256, 0, stream>>>(offs, bsum, cursor, N, E);
  k_fill<<<ge, 256, 0, stream>>>(edges, flag, cursor, epair, E);
  k_repack<<<160, 256, 0, stream>>>(W1, W2, W3, h1, l1, h2, l2, h3, l3);

  int gm = (N + 63) / 64;
  // layer 1: z1 = x @ W1   (bf16 out)
  k_gemm_mfma<128><<<gm, 256, 0, stream>>>(x, h1, l1, z1, N);
  // layer 2 fused: a1 = b1 + z1 + agg(z1) (LDS); z2 = relu(a1) @ W2
  k_fused<128><<<gm, 256, 0, stream>>>(z1, epair, offs, b1, h2, l2, z2, N);
  // layer 3 fused: a2 = b2 + z2 + agg(z2) (LDS); z3 = relu(a2) @ W3
  k_fused<64><<<gm, 256, 0, stream>>>(z2, epair, offs, b2, h3, l3, z3, N);
  // final agg: out = b3 + z3 + agg(z3)   (fp32 out)
  k_agg64<<<gm, 256, 0, stream>>>(z3, epair, offs, b3, out, N);
}

// Round 6
// 321.675 us; speedup vs baseline: 4.5189x; 4.5189x over previous
//
#include <hip/hip_runtime.h>

// ---------------------------------------------------------------------------
// GIN 3-layer: h_{l+1} = act((h + agg(h)) @ W + b)
// Restructured: z = act(h) @ W ; a = b + z + agg(z)   (agg commutes with W)
// Round 6: SPLIT-WAVE gather. 512-thread blocks, 8 waves:
//   waves 0-3: rows w*16.., edges [s,mid), init = bias + z_own
//   waves 4-7: same rows,   edges [mid,e), init = 0
//   partials combined via plain LDS tile (NO atomics - LDS f32 atomics are
//   lane-serialized ~4cy/lane, confirmed twice: r1 generic-CAS and r5
//   ds_add both land at ~500us/layer), then MFMA epilogue on waves 0-3.
// Rationale: gather is latency-bound; per-wave loop runs max(deg over 16
// nodes)~11.5 vs mean 6. Split halves the serial depth AND doubles the
// gathering waves per CU.
// ---------------------------------------------------------------------------

typedef __attribute__((ext_vector_type(8))) short short8;
typedef __attribute__((ext_vector_type(4))) float f32x4;
typedef unsigned short ushort_t;
typedef unsigned int uint_t;

__device__ inline ushort_t bf16_rne(float f) {
  uint_t u = __float_as_uint(f);
  uint_t r = (u + 0x7FFFu + ((u >> 16) & 1u)) >> 16;
  return (ushort_t)r;
}
__device__ inline float bf16_to_f32(ushort_t h) {
  return __uint_as_float(((uint_t)h) << 16);
}

// ---- edge dtype detection: int64 (reference decl) vs int32 (JAX x64-off) ----
__global__ __launch_bounds__(256) void k_detect(const int* __restrict__ ew,
                                                int* __restrict__ flag, int E) {
  int i = blockIdx.x * 256 + threadIdx.x;
  int idx = 2 * i + 1;
  if (idx < 2 * E) {
    if (ew[idx] != 0) atomicOr(flag, 1);    // nonzero odd word => int32 layout
  }
}

// ---- CSR build (reads edges directly, no staging) ---------------------------
__global__ __launch_bounds__(256) void k_hist(const void* __restrict__ edges,
                                              const int* __restrict__ flag,
                                              int* __restrict__ counts, int E) {
  int e = blockIdx.x * 256 + threadIdx.x;
  if (e >= E) return;
  int d;
  if (*flag) d = ((const int*)edges)[E + e];
  else       d = (int)((const long long*)edges)[E + e];
  atomicAdd(&counts[d], 1);
}

__global__ __launch_bounds__(256) void k_scan1(const int* __restrict__ counts,
                                               int* __restrict__ offs,
                                               int* __restrict__ bsum, int N) {
  __shared__ int s[256];
  int t = threadIdx.x;
  int base = blockIdx.x * 1024 + t * 4;
  int c0 = 0, c1 = 0, c2 = 0, c3 = 0;
  if (base + 0 < N) c0 = counts[base + 0];
  if (base + 1 < N) c1 = counts[base + 1];
  if (base + 2 < N) c2 = counts[base + 2];
  if (base + 3 < N) c3 = counts[base + 3];
  int mySum = c0 + c1 + c2 + c3;
  s[t] = mySum;
  __syncthreads();
  for (int d = 1; d < 256; d <<= 1) {
    int v = (t >= d) ? s[t - d] : 0;
    __syncthreads();
    s[t] += v;
    __syncthreads();
  }
  int excl = s[t] - mySum;
  if (base + 0 < N) offs[base + 0] = excl;
  if (base + 1 < N) offs[base + 1] = excl + c0;
  if (base + 2 < N) offs[base + 2] = excl + c0 + c1;
  if (base + 3 < N) offs[base + 3] = excl + c0 + c1 + c2;
  if (t == 255) bsum[blockIdx.x] = s[255];
}

__global__ __launch_bounds__(128) void k_scan2(int* __restrict__ bsum, int nb) {
  __shared__ int s[128];
  int t = threadIdx.x;
  int v = (t < nb) ? bsum[t] : 0;
  s[t] = v;
  __syncthreads();
  for (int d = 1; d < 128; d <<= 1) {
    int u = (t >= d) ? s[t - d] : 0;
    __syncthreads();
    s[t] += u;
    __syncthreads();
  }
  if (t < nb) bsum[t] = s[t] - v;
}

__global__ __launch_bounds__(256) void k_scan3(int* __restrict__ offs,
                                               const int* __restrict__ bsum,
                                               int* __restrict__ cursor,
                                               int N, int E) {
  int t = threadIdx.x;
  int add = bsum[blockIdx.x];
  int base = blockIdx.x * 1024 + t * 4;
#pragma unroll
  for (int j = 0; j < 4; j++) {
    int i = base + j;
    if (i < N) { int v = offs[i] + add; offs[i] = v; cursor[i] = v; }
  }
  if (blockIdx.x == 0 && t == 0) offs[N] = E;
}

__global__ __launch_bounds__(256) void k_fill(const void* __restrict__ edges,
                                              const int* __restrict__ flag,
                                              int* __restrict__ cursor,
                                              int* __restrict__ csr, int E) {
  int e = blockIdx.x * 256 + threadIdx.x;
  if (e >= E) return;
  int s, d;
  if (*flag) {
    const int* p = (const int*)edges;
    s = p[e]; d = p[E + e];
  } else {
    const long long* p = (const long long*)edges;
    s = (int)p[e]; d = (int)p[E + e];
  }
  int pos = atomicAdd(&cursor[d], 1);
  csr[pos] = s;
}

// ---- W repack into MFMA B-fragment order (hi/lo split bf16) -----------------
__global__ __launch_bounds__(256) void k_repack(
    const float* __restrict__ W1, const float* __restrict__ W2,
    const float* __restrict__ W3,
    ushort_t* __restrict__ h1, ushort_t* __restrict__ l1,
    ushort_t* __restrict__ h2, ushort_t* __restrict__ l2,
    ushort_t* __restrict__ h3, ushort_t* __restrict__ l3) {
  int idx = blockIdx.x * 256 + threadIdx.x;
  const float* W; ushort_t* H; ushort_t* L; int NC; int i;
  if (idx < 16384)      { W = W1; H = h1; L = l1; NC = 128; i = idx; }
  else if (idx < 32768) { W = W2; H = h2; L = l2; NC = 128; i = idx - 16384; }
  else if (idx < 40960) { W = W3; H = h3; L = l3; NC = 64;  i = idx - 32768; }
  else return;
  int j = i & 7;
  int lane = (i >> 3) & 63;
  int NT = NC >> 4;
  int tile = (i >> 9) & (NT - 1);
  int ks = i >> (9 + (NC == 128 ? 3 : 2));
  int k = ks * 32 + (lane >> 4) * 8 + j;
  int n = tile * 16 + (lane & 15);
  float v = W[(size_t)k * NC + n];
  ushort_t hi = bf16_rne(v);
  ushort_t lo = bf16_rne(v - bf16_to_f32(hi));
  H[i] = hi; L[i] = lo;
}

// ---- layer 1 GEMM: Z(bf16)[M x NC] = A(fp32)[M x 128] @ W -------------------
template <int NC>
__global__ __launch_bounds__(256) void k_gemm_mfma(
    const float* __restrict__ A, const ushort_t* __restrict__ Bhi,
    const ushort_t* __restrict__ Blo, ushort_t* __restrict__ Z, int M) {
  constexpr int NT = NC / 16;
  int lane = threadIdx.x & 63;
  int wave = threadIdx.x >> 6;
  int row0 = blockIdx.x * 64 + wave * 16;
  int m = lane & 15;
  int q = lane >> 4;
  int grow = row0 + m;
  bool rowok = (grow < M);

  f32x4 acc[NT];
#pragma unroll
  for (int t = 0; t < NT; t++) { acc[t][0] = 0.f; acc[t][1] = 0.f; acc[t][2] = 0.f; acc[t][3] = 0.f; }

  const float* arow = A + (size_t)(rowok ? grow : 0) * 128 + q * 8;

#pragma unroll
  for (int ks = 0; ks < 4; ks++) {
    float av[8];
    *(float4*)(av)     = *(const float4*)(arow + ks * 32);
    *(float4*)(av + 4) = *(const float4*)(arow + ks * 32 + 4);
    short8 ahi, alo;
#pragma unroll
    for (int j = 0; j < 8; j++) {
      float v = av[j];
      ushort_t hi = bf16_rne(v);
      ahi[j] = (short)hi;
      alo[j] = (short)bf16_rne(v - bf16_to_f32(hi));
    }
#pragma unroll
    for (int t = 0; t < NT; t++) {
      const short8 bh = *(const short8*)(Bhi + (((size_t)ks * NT + t) * 64 + lane) * 8);
      const short8 bl = *(const short8*)(Blo + (((size_t)ks * NT + t) * 64 + lane) * 8);
      acc[t] = __builtin_amdgcn_mfma_f32_16x16x32_bf16(ahi, bh, acc[t], 0, 0, 0);
      acc[t] = __builtin_amdgcn_mfma_f32_16x16x32_bf16(ahi, bl, acc[t], 0, 0, 0);
      acc[t] = __builtin_amdgcn_mfma_f32_16x16x32_bf16(alo, bh, acc[t], 0, 0, 0);
    }
  }

  int zrow = row0 + q * 4;
#pragma unroll
  for (int r = 0; r < 4; r++) {
    if (zrow + r < M) {
#pragma unroll
      for (int t = 0; t < NT; t++)
        Z[(size_t)(zrow + r) * NC + t * 16 + m] = bf16_rne(acc[t][r]);
    }
  }
}

// ---- fused agg + GEMM (layers 2,3): split-wave gather -----------------------
// 512 threads / 8 waves. Wave w (w<4) and wave w+4 both own rows w*16..w*16+15;
// they split each node's edge list at mid. Wave w: [s,mid) + bias + z_own.
// Wave w+4: [mid,e) into zeroed regs -> LDS partial -> combined by wave w.
template <int NC>
__global__ __launch_bounds__(512, 4) void k_fused(
    const ushort_t* __restrict__ Zin, const int* __restrict__ csr,
    const int* __restrict__ offs, const float* __restrict__ bias,
    const ushort_t* __restrict__ Bhi, const ushort_t* __restrict__ Blo,
    ushort_t* __restrict__ Zout, int M) {
  constexpr int NT = NC / 16;
  constexpr int S = 132;
  __shared__ float sacc[64 * S];

  int t = threadIdx.x;
  int lane = t & 63;
  int wave = t >> 6;
  int wv = wave & 3;
  int half = wave >> 2;
  int row0 = blockIdx.x * 64 + wv * 16;
  int m = lane & 15;
  int q = lane >> 4;
  int grow = row0 + m;
  bool rowok = (grow < M);

  // accumulators a[grow][ks*32 + q*8 + j]
  float av[4][8];
  if (half == 0) {
    const ushort_t* zr0 = Zin + (size_t)(rowok ? grow : 0) * 128 + q * 8;
    const float* bq = bias + q * 8;
#pragma unroll
    for (int ks = 0; ks < 4; ks++) {
      float4 b0 = *(const float4*)(bq + ks * 32);
      float4 b1 = *(const float4*)(bq + ks * 32 + 4);
      short8 u = *(const short8*)(zr0 + ks * 32);
      av[ks][0] = b0.x + bf16_to_f32((ushort_t)u[0]);
      av[ks][1] = b0.y + bf16_to_f32((ushort_t)u[1]);
      av[ks][2] = b0.z + bf16_to_f32((ushort_t)u[2]);
      av[ks][3] = b0.w + bf16_to_f32((ushort_t)u[3]);
      av[ks][4] = b1.x + bf16_to_f32((ushort_t)u[4]);
      av[ks][5] = b1.y + bf16_to_f32((ushort_t)u[5]);
      av[ks][6] = b1.z + bf16_to_f32((ushort_t)u[6]);
      av[ks][7] = b1.w + bf16_to_f32((ushort_t)u[7]);
    }
  } else {
#pragma unroll
    for (int ks = 0; ks < 4; ks++)
#pragma unroll
      for (int jj = 0; jj < 8; jj++) av[ks][jj] = 0.f;
  }

  int s = 0, e = 0;
  if (rowok) { s = offs[grow]; e = offs[grow + 1]; }
  int mid = (s + e) >> 1;
  int j  = half ? mid : s;
  int je = half ? e   : mid;

  for (; j + 2 <= je; j += 2) {
    int i0 = csr[j], i1 = csr[j + 1];
    const ushort_t* za = Zin + (size_t)i0 * 128 + q * 8;
    const ushort_t* zb = Zin + (size_t)i1 * 128 + q * 8;
    short8 ua[4], ub[4];
#pragma unroll
    for (int ks = 0; ks < 4; ks++) ua[ks] = *(const short8*)(za + ks * 32);
#pragma unroll
    for (int ks = 0; ks < 4; ks++) ub[ks] = *(const short8*)(zb + ks * 32);
#pragma unroll
    for (int ks = 0; ks < 4; ks++)
#pragma unroll
      for (int jj = 0; jj < 8; jj++)
        av[ks][jj] += bf16_to_f32((ushort_t)ua[ks][jj]) +
                      bf16_to_f32((ushort_t)ub[ks][jj]);
  }
  if (j < je) {
    int i0 = csr[j];
    const ushort_t* za = Zin + (size_t)i0 * 128 + q * 8;
#pragma unroll
    for (int ks = 0; ks < 4; ks++) {
      short8 u = *(const short8*)(za + ks * 32);
#pragma unroll
      for (int jj = 0; jj < 8; jj++)
        av[ks][jj] += bf16_to_f32((ushort_t)u[jj]);
    }
  }

  // combine halves through LDS (plain writes, no atomics)
  if (half) {
    float* dst = sacc + (wv * 16 + m) * S + q * 8;
#pragma unroll
    for (int ks = 0; ks < 4; ks++)
#pragma unroll
      for (int jj = 0; jj < 8; jj += 2)
        *(float2*)(dst + ks * 32 + jj) = make_float2(av[ks][jj], av[ks][jj + 1]);
  }
  __syncthreads();
  if (half) return;
  {
    const float* src = sacc + (wv * 16 + m) * S + q * 8;
#pragma unroll
    for (int ks = 0; ks < 4; ks++)
#pragma unroll
      for (int jj = 0; jj < 8; jj += 2) {
        float2 p = *(const float2*)(src + ks * 32 + jj);
        av[ks][jj]     += p.x;
        av[ks][jj + 1] += p.y;
      }
  }

  // relu + split-bf16 + MFMA
  f32x4 acc[NT];
#pragma unroll
  for (int tt = 0; tt < NT; tt++) { acc[tt][0] = 0.f; acc[tt][1] = 0.f; acc[tt][2] = 0.f; acc[tt][3] = 0.f; }

#pragma unroll
  for (int ks = 0; ks < 4; ks++) {
    short8 ahi, alo;
#pragma unroll
    for (int jj = 0; jj < 8; jj++) {
      float v = fmaxf(av[ks][jj], 0.f);
      ushort_t hi = bf16_rne(v);
      ahi[jj] = (short)hi;
      alo[jj] = (short)bf16_rne(v - bf16_to_f32(hi));
    }
#pragma unroll
    for (int tt = 0; tt < NT; tt++) {
      const short8 bh = *(const short8*)(Bhi + (((size_t)ks * NT + tt) * 64 + lane) * 8);
      const short8 bl = *(const short8*)(Blo + (((size_t)ks * NT + tt) * 64 + lane) * 8);
      acc[tt] = __builtin_amdgcn_mfma_f32_16x16x32_bf16(ahi, bh, acc[tt], 0, 0, 0);
      acc[tt] = __builtin_amdgcn_mfma_f32_16x16x32_bf16(ahi, bl, acc[tt], 0, 0, 0);
      acc[tt] = __builtin_amdgcn_mfma_f32_16x16x32_bf16(alo, bh, acc[tt], 0, 0, 0);
    }
  }

  int zrow = row0 + q * 4;
#pragma unroll
  for (int r = 0; r < 4; r++) {
    if (zrow + r < M) {
#pragma unroll
      for (int tt = 0; tt < NT; tt++)
        Zout[(size_t)(zrow + r) * NC + tt * 16 + m] = bf16_rne(acc[tt][r]);
    }
  }
}

// ---- final agg (64 cols): split-wave gather ---------------------------------
// 512 threads: t<256 handles [s,mid)+bias+own, t>=256 handles [mid,e) -> LDS.
__global__ __launch_bounds__(512, 4) void k_agg64(const ushort_t* __restrict__ z,
                                                  const int* __restrict__ csr,
                                                  const int* __restrict__ offs,
                                                  const float* __restrict__ bias,
                                                  float* __restrict__ out, int N) {
  constexpr int S = 68;
  __shared__ float sacc[32 * S];
  int t = threadIdx.x;
  int half = t >> 8;
  int t2 = t & 255;
  int nl = t2 >> 3;                 // node-local 0..31
  int node = blockIdx.x * 32 + nl;
  bool nodeok = (node < N);
  int c = (t2 & 7) * 8;

  float acc[8];
  if (half == 0) {
    short8 u = *(const short8*)(z + (size_t)(nodeok ? node : 0) * 64 + c);
#pragma unroll
    for (int jj = 0; jj < 8; jj++)
      acc[jj] = bias[c + jj] + bf16_to_f32((ushort_t)u[jj]);
  } else {
#pragma unroll
    for (int jj = 0; jj < 8; jj++) acc[jj] = 0.f;
  }

  int s = 0, e = 0;
  if (nodeok) { s = offs[node]; e = offs[node + 1]; }
  int mid = (s + e) >> 1;
  int j  = half ? mid : s;
  int je = half ? e   : mid;

  for (; j + 2 <= je; j += 2) {
    int i0 = csr[j], i1 = csr[j + 1];
    short8 u0 = *(const short8*)(z + (size_t)i0 * 64 + c);
    short8 u1 = *(const short8*)(z + (size_t)i1 * 64 + c);
#pragma unroll
    for (int jj = 0; jj < 8; jj++)
      acc[jj] += bf16_to_f32((ushort_t)u0[jj]) + bf16_to_f32((ushort_t)u1[jj]);
  }
  if (j < je) {
    int i0 = csr[j];
    short8 u = *(const short8*)(z + (size_t)i0 * 64 + c);
#pragma unroll
    for (int jj = 0; jj < 8; jj++)
      acc[jj] += bf16_to_f32((ushort_t)u[jj]);
  }

  if (half) {
    float* dst = sacc + nl * S + c;
#pragma unroll
    for (int jj = 0; jj < 8; jj += 2)
      *(float2*)(dst + jj) = make_float2(acc[jj], acc[jj + 1]);
  }
  __syncthreads();
  if (half) return;
  {
    const float* sp = sacc + nl * S + c;
#pragma unroll
    for (int jj = 0; jj < 8; jj += 2) {
      float2 p = *(const float2*)(sp + jj);
      acc[jj]     += p.x;
      acc[jj + 1] += p.y;
    }
  }

  if (nodeok) {
    float4 o0 = make_float4(acc[0], acc[1], acc[2], acc[3]);
    float4 o1 = make_float4(acc[4], acc[5], acc[6], acc[7]);
    *(float4*)&out[(size_t)node * 64 + c]     = o0;
    *(float4*)&out[(size_t)node * 64 + c + 4] = o1;
  }
}

// ---------------------------------------------------------------------------
extern "C" void kernel_launch(void* const* d_in, const int* in_sizes, int n_in,
                              void* d_out, int out_size, void* d_ws, size_t ws_size,
                              hipStream_t stream) {
  const float* x  = (const float*)d_in[0];
  const void* edges = d_in[1];
  const float* W1 = (const float*)d_in[2];
  const float* b1 = (const float*)d_in[3];
  const float* W2 = (const float*)d_in[4];
  const float* b2 = (const float*)d_in[5];
  const float* W3 = (const float*)d_in[6];
  const float* b3 = (const float*)d_in[7];
  float* out = (float*)d_out;

  int N = in_sizes[0] / 128;   // 100000
  int E = in_sizes[1] / 2;     // 600000

  char* w = (char*)d_ws;
  size_t off = 0;
  auto alloc = [&](size_t bytes) -> void* {
    void* p = w + off;
    off = (off + bytes + 255) & ~(size_t)255;
    return p;
  };
  size_t curBytes = ((size_t)N * 4 + 255) & ~(size_t)255;
  int*   cursor = (int*)alloc(curBytes);     // degree counts, then fill cursor
  int*   flag   = (int*)alloc(4);            // adjacent: one memset covers both
  int*   csr    = (int*)alloc((size_t)E * 4);
  int*   offs   = (int*)alloc((size_t)(N + 1) * 4);
  int*   bsum   = (int*)alloc(4096);
  ushort_t* h1  = (ushort_t*)alloc(16384 * 2);
  ushort_t* l1  = (ushort_t*)alloc(16384 * 2);
  ushort_t* h2  = (ushort_t*)alloc(16384 * 2);
  ushort_t* l2  = (ushort_t*)alloc(16384 * 2);
  ushort_t* h3  = (ushort_t*)alloc(8192 * 2);
  ushort_t* l3  = (ushort_t*)alloc(8192 * 2);
  ushort_t* z1  = (ushort_t*)alloc((size_t)N * 128 * 2);  // bf16
  ushort_t* z2  = (ushort_t*)alloc((size_t)N * 128 * 2);  // bf16
  ushort_t* z3  = z1;                                     // reuse (N x 64 fits)

  int ge = (E + 255) / 256;
  int nb = (N + 1023) / 1024;

  hipMemsetAsync(cursor, 0, curBytes + 4, stream);
  k_detect<<<4, 256, 0, stream>>>((const int*)edges, flag, E);
  k_hist<<<ge, 256, 0, stream>>>(edges, flag, cursor, E);
  k_scan1<<<nb, 256, 0, stream>>>(cursor, offs, bsum, N);
  k_scan2<<<1, 128, 0, stream>>>(bsum, nb);
  k_scan3<<<nb, 256, 0, stream>>>(offs, bsum, cursor, N, E);
  k_fill<<<ge, 256, 0, stream>>>(edges, flag, cursor, csr, E);
  k_repack<<<160, 256, 0, stream>>>(W1, W2, W3, h1, l1, h2, l2, h3, l3);

  int gm = (N + 63) / 64;
  // layer 1: z1 = x @ W1   (bf16 out)
  k_gemm_mfma<128><<<gm, 256, 0, stream>>>(x, h1, l1, z1, N);
  // layer 2 fused: a1 = b1 + z1 + agg(z1); z2 = relu(a1) @ W2
  k_fused<128><<<gm, 512, 0, stream>>>(z1, csr, offs, b1, h2, l2, z2, N);
  // layer 3 fused: a2 = b2 + z2 + agg(z2); z3 = relu(a2) @ W3
  k_fused<64><<<gm, 512, 0, stream>>>(z2, csr, offs, b2, h3, l3, z3, N);
  // final agg: out = b3 + z3 + agg(z3)   (fp32 out)
  k_agg64<<<(N + 31) / 32, 512, 0, stream>>>(z3, csr, offs, b3, out, N);
}